// Round 6
// baseline (106.086 us; speedup 1.0000x reference)
//
#include <hip/hip_runtime.h>

typedef float f32x4 __attribute__((ext_vector_type(4)));
typedef int   i32x4 __attribute__((ext_vector_type(4)));
typedef int   i32x8 __attribute__((ext_vector_type(8)));
typedef unsigned short ushort_t;

#define T_LEN 128
#define BATCH 64
#define M_TOK 8192   // BATCH * T_LEN
#define HDIM  128
#define SQRT_LOG2E 1.2011224087864498f  // (s*xi).(s*xj) = log2(e)*xi.xj
#define M_LN2_F 0.6931471805599453f

// 2^t Taylor deg-4 restructured: 2^t ~= 1 + t*q(t),
// q(t) = C1 + t*(C2 + t*(C3 + t*C4)); "+1"s folded into rsv init (16.0f).
#define P_C1 0.6931471806f
#define P_C2 0.2402265070f
#define P_C3 0.0555041087f
#define P_C4 0.0096181291f

// Fragment-major layout for 16x16x128 f8f6f4 MFMA:
// xsw[T][quad][col][32B]  (strides 2048 / 512 / 32 bytes)
// = bytes [quad*32, quad*32+32) of token (16*T + col), fp8 e4m3, pre-scaled.

// Kernel A: identical to R12.
__global__ __launch_bounds__(256) void prep_kernel(const float* __restrict__ hs,
                                                   unsigned char* __restrict__ xsw,
                                                   float* __restrict__ pos,
                                                   float* __restrict__ ns,
                                                   unsigned int* __restrict__ counter) {
    int wave = threadIdx.x >> 6;
    int lane = threadIdx.x & 63;
    int i = blockIdx.x * 4 + wave;
    int t = i & (T_LEN - 1);
    const float* row = hs + (size_t)i * HDIM;
    float2 x = *(const float2*)(row + 2 * lane);
    unsigned int pk = __builtin_amdgcn_cvt_pk_fp8_f32(x.x * SQRT_LOG2E,
                                                      x.y * SQRT_LOG2E, 0, false);
    {
        int Ti  = i >> 4;
        int c   = i & 15;
        int qd  = lane >> 4;            // (2*lane) / 32
        int off = (2 * lane) & 31;      // within the 32B chunk (even)
        *(ushort_t*)(xsw + (size_t)Ti * 2048 + qd * 512 + c * 32 + off) = (ushort_t)pk;
    }
    float acc = 0.f;
    if (t > 0) {
        float2 p = *(const float2*)(row - HDIM + 2 * lane);
        acc += x.x * p.x + x.y * p.y;
    }
    if (t < T_LEN - 1) {
        float2 n = *(const float2*)(row + HDIM + 2 * lane);
        acc += x.x * n.x + x.y * n.y;
    }
    for (int m = 32; m; m >>= 1) acc += __shfl_xor(acc, m);
    if (lane == 0) { pos[i] = acc; ns[i] = 0.f; }
    if (blockIdx.x == 0 && threadIdx.x == 0) counter[0] = 0u;
}

__device__ inline i32x8 load_frag32(const unsigned char* p) {
    i32x4 lo = *(const i32x4*)p;
    i32x4 hi = *(const i32x4*)(p + 16);
    return __builtin_shufflevector(lo, hi, 0, 1, 2, 3, 4, 5, 6, 7);
}

// Kernel B (R16 DIAGNOSTIC): exact R12 body executed TWICE (rep loop with
// a memory clobber between reps to defeat CSE -- loads, MFMAs, poly and
// the atomic scatter all run twice). ns accumulates 2x the true sum; fin
// corrects exactly via log(2x) = log(x) + ln2.
// Purpose: (1) Delta(total) vs R12 = one true negsum pass duration;
// (2) if negsum >= ~21 us, the doubled dispatch (>=42 us) enters the
// rocprof top-5 and exposes its real MfmaUtil/VALUBusy/Occupancy/FETCH.
__global__ __launch_bounds__(256) void negsum_kernel(const unsigned char* __restrict__ xsw,
                                                     float* __restrict__ ns) {
    int tid  = threadIdx.x;
    int wave = tid >> 6;
    int lane = tid & 63;
    int col  = lane & 15;
    int quad = lane >> 4;
    int rg   = blockIdx.x;                 // row group (256 rows)
    int cs   = blockIdx.y;                 // column split 0..31 (shared by waves)
    int laneoff = quad * 512 + col * 32;
    int rot  = rg & 15;                    // tile-order rotation (stagger same-cs readers)
    const int sc = 0x7F7F7F7F;             // E8M0 scale 127 -> x1.0

    for (int rep = 0; rep < 2; ++rep) {
        // A frags: row tiles rg*16 + wave*4 .. +3 (8 VGPRs each)
        int rowtile = rg * 16 + wave * 4;
        i32x8 afr[4];
        #pragma unroll
        for (int rb = 0; rb < 4; ++rb)
            afr[rb] = load_frag32(xsw + (size_t)(rowtile + rb) * 2048 + laneoff);

        f32x4 rsv[4];
        #pragma unroll
        for (int rb = 0; rb < 4; ++rb) rsv[rb] = (f32x4){16.f, 16.f, 16.f, 16.f};

        const unsigned char* bptr = xsw + (size_t)(cs * 16) * 2048 + laneoff;

        i32x8 bf[4];                       // 4-deep prefetch ring
        #pragma unroll
        for (int p = 0; p < 4; ++p)
            bf[p] = load_frag32(bptr + (size_t)(((rot + p) & 15)) * 2048);

        #pragma unroll
        for (int i = 0; i < 16; ++i) {
            int slot = i & 3;
            f32x4 d[4];
            #pragma unroll
            for (int rb = 0; rb < 4; ++rb)
                d[rb] = __builtin_amdgcn_mfma_scale_f32_16x16x128_f8f6f4(
                    afr[rb], bf[slot], (f32x4){0.f, 0.f, 0.f, 0.f}, 0, 0, 0, sc, 0, sc);
            if (i + 4 < 16)
                bf[slot] = load_frag32(bptr + (size_t)(((rot + i + 4) & 15)) * 2048);
            #pragma unroll
            for (int rb = 0; rb < 4; ++rb) {
                f32x4 v = d[rb];           // log2(e) * x_row . x_col
                f32x4 q = v * P_C4 + P_C3; // deg-3 Horner for q(t)
                q = q * v + P_C2;
                q = q * v + P_C1;
                rsv[rb] = q * v + rsv[rb]; // exp ~= 1 + v*q; "+1" in rsv init
            }
        }

        // reduce across the 16 column-lanes within each quad group
        #pragma unroll
        for (int m = 1; m < 16; m <<= 1)
            #pragma unroll
            for (int rb = 0; rb < 4; ++rb)
                #pragma unroll
                for (int r = 0; r < 4; ++r)
                    rsv[rb][r] += __shfl_xor(rsv[rb][r], m);

        if (col == 0) {
            #pragma unroll
            for (int rb = 0; rb < 4; ++rb)
                #pragma unroll
                for (int r = 0; r < 4; ++r)
                    atomicAdd(ns + (size_t)(rg * 256 + wave * 64 + rb * 16 + quad * 4 + r),
                              rsv[rb][r]);
        }
        asm volatile("" ::: "memory");     // defeat cross-rep CSE: full recompute
    }
}

// Kernel C: R12 fin + exact ln2 correction for the doubled ns.
__global__ __launch_bounds__(128) void fin_kernel(const float* __restrict__ ns,
                                                  const float* __restrict__ pos,
                                                  const int* __restrict__ dia,
                                                  float* __restrict__ bpart,
                                                  unsigned int* __restrict__ counter,
                                                  float* __restrict__ out) {
    __shared__ float s2[2];
    __shared__ int slast;
    int b = blockIdx.x;
    int t = threadIdx.x;
    int len = dia[b];
    int i = b * T_LEN + t;
    float acc = (t < len - 1) ? (__logf(ns[i]) - M_LN2_F - pos[i]) : 0.f;
    for (int m = 32; m; m >>= 1) acc += __shfl_xor(acc, m);
    if ((t & 63) == 0) s2[t >> 6] = acc;
    __syncthreads();
    if (t == 0) {
        bpart[b] = s2[0] + s2[1];
        __threadfence();                               // release bpart[b]
        slast = (atomicAdd(counter, 1u) == BATCH - 1);
    }
    __syncthreads();
    if (slast && t < 64) {
        __threadfence();                               // acquire others' bpart
        float s = bpart[t];
        int c = dia[t] - 1;
        for (int m = 32; m; m >>= 1) {
            s += __shfl_xor(s, m);
            c += __shfl_xor(c, m);
        }
        if (t == 0) out[0] = s / (float)c;
    }
}

extern "C" void kernel_launch(void* const* d_in, const int* in_sizes, int n_in,
                              void* d_out, int out_size, void* d_ws, size_t ws_size,
                              hipStream_t stream) {
    const float* hs  = (const float*)d_in[0];
    // d_in[1] = mask (implied by dia_lens; unused)
    const int*   dia = (const int*)d_in[2];
    float* out = (float*)d_out;

    unsigned char* xsw = (unsigned char*)d_ws;                         // 1 MB fragment-major fp8
    float* pos    = (float*)((char*)d_ws + 1048576);                   // 32 KB
    float* ns     = (float*)((char*)d_ws + 1048576 + 32768);           // 32 KB accumulated negsum
    float* bpart  = (float*)((char*)d_ws + 1048576 + 65536);           // 256 B
    unsigned int* counter = (unsigned int*)((char*)d_ws + 1048576 + 65536 + 256);

    prep_kernel<<<M_TOK / 4, 256, 0, stream>>>(hs, xsw, pos, ns, counter);
    negsum_kernel<<<dim3(32, 32), 256, 0, stream>>>(xsw, ns);
    fin_kernel<<<BATCH, 128, 0, stream>>>(ns, pos, dia, bpart, counter, out);
}

// Round 7
// 81.984 us; speedup vs baseline: 1.2940x; 1.2940x over previous
//
#include <hip/hip_runtime.h>

typedef float f32x4 __attribute__((ext_vector_type(4)));
typedef int   i32x4 __attribute__((ext_vector_type(4)));
typedef int   i32x8 __attribute__((ext_vector_type(8)));
typedef unsigned short ushort_t;

#define T_LEN 128
#define BATCH 64
#define M_TOK 8192   // BATCH * T_LEN
#define HDIM  128
#define SQRT_LOG2E 1.2011224087864498f  // (s*xi).(s*xj) = log2(e)*xi.xj

// 2^t Taylor deg-4 restructured: 2^t ~= 1 + t*q(t),
// q(t) = C1 + t*(C2 + t*(C3 + t*C4)); "+1"s folded into rsv init (16.0f).
#define P_C1 0.6931471806f
#define P_C2 0.2402265070f
#define P_C3 0.0555041087f
#define P_C4 0.0096181291f

// Fragment-major layout for 16x16x128 f8f6f4 MFMA:
// xsw[T][quad][col][32B]  (strides 2048 / 512 / 32 bytes)
// = bytes [quad*32, quad*32+32) of token (16*T + col), fp8 e4m3, pre-scaled.
// A lane's 32B fragment of tile T = 16B units lu = 2*lane, 2*lane+1 of T.

// Kernel A: identical to R12.
__global__ __launch_bounds__(256) void prep_kernel(const float* __restrict__ hs,
                                                   unsigned char* __restrict__ xsw,
                                                   float* __restrict__ pos,
                                                   float* __restrict__ ns,
                                                   unsigned int* __restrict__ counter) {
    int wave = threadIdx.x >> 6;
    int lane = threadIdx.x & 63;
    int i = blockIdx.x * 4 + wave;
    int t = i & (T_LEN - 1);
    const float* row = hs + (size_t)i * HDIM;
    float2 x = *(const float2*)(row + 2 * lane);
    unsigned int pk = __builtin_amdgcn_cvt_pk_fp8_f32(x.x * SQRT_LOG2E,
                                                      x.y * SQRT_LOG2E, 0, false);
    {
        int Ti  = i >> 4;
        int c   = i & 15;
        int qd  = lane >> 4;            // (2*lane) / 32
        int off = (2 * lane) & 31;      // within the 32B chunk (even)
        *(ushort_t*)(xsw + (size_t)Ti * 2048 + qd * 512 + c * 32 + off) = (ushort_t)pk;
    }
    float acc = 0.f;
    if (t > 0) {
        float2 p = *(const float2*)(row - HDIM + 2 * lane);
        acc += x.x * p.x + x.y * p.y;
    }
    if (t < T_LEN - 1) {
        float2 n = *(const float2*)(row + HDIM + 2 * lane);
        acc += x.x * n.x + x.y * n.y;
    }
    for (int m = 32; m; m >>= 1) acc += __shfl_xor(acc, m);
    if (lane == 0) { pos[i] = acc; ns[i] = 0.f; }
    if (blockIdx.x == 0 && threadIdx.x == 0) counter[0] = 0u;
}

__device__ inline i32x8 load_frag32(const unsigned char* p) {
    i32x4 lo = *(const i32x4*)p;
    i32x4 hi = *(const i32x4*)(p + 16);
    return __builtin_shufflevector(lo, hi, 0, 1, 2, 3, 4, 5, 6, 7);
}

// Kernel B (R17): ONE change vs R12 -- B operands come from LDS, not the
// vmem path. R16 diag showed one negsum pass ~= 28 us, occupancy- and
// work-insensitive, HBM ~0: theory = per-CU L1/TA miss-path saturation
// (16 waves x 16 iters x 2 dwordx4 x 16 lines ~= 8192 line-requests/CU).
// Fix: stage the block's 32 KB B-slab (16 tiles) into LDS once via
// reg-staging (8 coalesced dwordx4 rounds/thread + ds_write_b128), then
// each iter reads its fragment as 2x ds_read_b128.
//  - XOR swizzle p = lu ^ ((lu>>3)&7) on 16B units within each 128-unit
//    tile: bijective; write side (consecutive lu) stays conflict-free;
//    read side (lu = 2*lane+h) spreads every 8-lane group over all 32
//    banks exactly once -> 8-sweep floor, conflict-free.
//  - kills the 4-deep prefetch ring + rot addressing (fewer VGPRs).
//  - vmem line-requests per CU drop 4x; per-iter B fetch moves to DS pipe
//    (~1.7 us/CU total, off the suspected critical path).
// Everything else (grid (32,32), cs shared by 4 waves, A frags in regs,
// deg-3 Horner q, quad-group reduce, atomicAdd ns) is exact R12.
__global__ __launch_bounds__(256) void negsum_kernel(const unsigned char* __restrict__ xsw,
                                                     float* __restrict__ ns) {
    __shared__ unsigned char btile[32768];   // 16 tiles x 2048 B, unit-swizzled
    int tid  = threadIdx.x;
    int wave = tid >> 6;
    int lane = tid & 63;
    int col  = lane & 15;
    int quad = lane >> 4;
    int rg   = blockIdx.x;                 // row group (256 rows)
    int cs   = blockIdx.y;                 // column split 0..31 (shared by waves)
    int laneoff = quad * 512 + col * 32;
    const int sc = 0x7F7F7F7F;             // E8M0 scale 127 -> x1.0

    // ---- stage B slab: 32 KB = 2048 units of 16 B ----
    const unsigned char* bsrc = xsw + (size_t)(cs * 16) * 2048;
    #pragma unroll
    for (int r = 0; r < 8; ++r) {
        int u    = r * 256 + tid;          // global unit in the slab
        int tile = u >> 7;
        int lu   = u & 127;
        i32x4 v  = *(const i32x4*)(bsrc + (size_t)u * 16);
        int pu   = lu ^ ((lu >> 3) & 7);   // bijective within tile
        *(i32x4*)&btile[tile * 2048 + pu * 16] = v;
    }

    // A frags: row tiles rg*16 + wave*4 .. +3 (loop-invariant, 8 VGPRs each)
    int rowtile = rg * 16 + wave * 4;
    i32x8 afr[4];
    #pragma unroll
    for (int rb = 0; rb < 4; ++rb)
        afr[rb] = load_frag32(xsw + (size_t)(rowtile + rb) * 2048 + laneoff);

    f32x4 rsv[4];
    #pragma unroll
    for (int rb = 0; rb < 4; ++rb) rsv[rb] = (f32x4){16.f, 16.f, 16.f, 16.f};

    // swizzled byte offsets of this lane's two 16B units (tile-invariant)
    int l2 = lane * 2;
    int cx = (l2 >> 3) & 7;                // same for l2 and l2+1 (l2 even)
    int p0 = (l2 ^ cx) * 16;
    int p1 = ((l2 + 1) ^ cx) * 16;

    __syncthreads();                       // B slab visible to all waves

    #pragma unroll
    for (int i = 0; i < 16; ++i) {
        i32x4 lo = *(const i32x4*)&btile[i * 2048 + p0];
        i32x4 hi = *(const i32x4*)&btile[i * 2048 + p1];
        i32x8 bfr = __builtin_shufflevector(lo, hi, 0, 1, 2, 3, 4, 5, 6, 7);
        f32x4 d[4];
        #pragma unroll
        for (int rb = 0; rb < 4; ++rb)
            d[rb] = __builtin_amdgcn_mfma_scale_f32_16x16x128_f8f6f4(
                afr[rb], bfr, (f32x4){0.f, 0.f, 0.f, 0.f}, 0, 0, 0, sc, 0, sc);
        #pragma unroll
        for (int rb = 0; rb < 4; ++rb) {
            f32x4 v = d[rb];               // log2(e) * x_row . x_col
            f32x4 q = v * P_C4 + P_C3;     // deg-3 Horner for q(t)
            q = q * v + P_C2;
            q = q * v + P_C1;
            rsv[rb] = q * v + rsv[rb];     // exp ~= 1 + v*q; "+1" in rsv init
        }
    }

    // reduce across the 16 column-lanes within each quad group
    #pragma unroll
    for (int m = 1; m < 16; m <<= 1)
        #pragma unroll
        for (int rb = 0; rb < 4; ++rb)
            #pragma unroll
            for (int r = 0; r < 4; ++r)
                rsv[rb][r] += __shfl_xor(rsv[rb][r], m);

    if (col == 0) {
        #pragma unroll
        for (int rb = 0; rb < 4; ++rb)
            #pragma unroll
            for (int r = 0; r < 4; ++r)
                atomicAdd(ns + (size_t)(rg * 256 + wave * 64 + rb * 16 + quad * 4 + r),
                          rsv[rb][r]);
    }
}

// Kernel C: exact R12 fin.
__global__ __launch_bounds__(128) void fin_kernel(const float* __restrict__ ns,
                                                  const float* __restrict__ pos,
                                                  const int* __restrict__ dia,
                                                  float* __restrict__ bpart,
                                                  unsigned int* __restrict__ counter,
                                                  float* __restrict__ out) {
    __shared__ float s2[2];
    __shared__ int slast;
    int b = blockIdx.x;
    int t = threadIdx.x;
    int len = dia[b];
    int i = b * T_LEN + t;
    float acc = (t < len - 1) ? (__logf(ns[i]) - pos[i]) : 0.f;
    for (int m = 32; m; m >>= 1) acc += __shfl_xor(acc, m);
    if ((t & 63) == 0) s2[t >> 6] = acc;
    __syncthreads();
    if (t == 0) {
        bpart[b] = s2[0] + s2[1];
        __threadfence();                               // release bpart[b]
        slast = (atomicAdd(counter, 1u) == BATCH - 1);
    }
    __syncthreads();
    if (slast && t < 64) {
        __threadfence();                               // acquire others' bpart
        float s = bpart[t];
        int c = dia[t] - 1;
        for (int m = 32; m; m >>= 1) {
            s += __shfl_xor(s, m);
            c += __shfl_xor(c, m);
        }
        if (t == 0) out[0] = s / (float)c;
    }
}

extern "C" void kernel_launch(void* const* d_in, const int* in_sizes, int n_in,
                              void* d_out, int out_size, void* d_ws, size_t ws_size,
                              hipStream_t stream) {
    const float* hs  = (const float*)d_in[0];
    // d_in[1] = mask (implied by dia_lens; unused)
    const int*   dia = (const int*)d_in[2];
    float* out = (float*)d_out;

    unsigned char* xsw = (unsigned char*)d_ws;                         // 1 MB fragment-major fp8
    float* pos    = (float*)((char*)d_ws + 1048576);                   // 32 KB
    float* ns     = (float*)((char*)d_ws + 1048576 + 32768);           // 32 KB accumulated negsum
    float* bpart  = (float*)((char*)d_ws + 1048576 + 65536);           // 256 B
    unsigned int* counter = (unsigned int*)((char*)d_ws + 1048576 + 65536 + 256);

    prep_kernel<<<M_TOK / 4, 256, 0, stream>>>(hs, xsw, pos, ns, counter);
    negsum_kernel<<<dim3(32, 32), 256, 0, stream>>>(xsw, ns);
    fin_kernel<<<BATCH, 128, 0, stream>>>(ns, pos, dia, bpart, counter, out);
}